// Round 1
// baseline (140.479 us; speedup 1.0000x reference)
//
#include <hip/hip_runtime.h>
#include <hip/hip_cooperative_groups.h>
#include <math.h>

namespace cg = cooperative_groups;

#define NS     32768             // samples per sequence
#define NB     128               // interpolation bins
#define CELL   32                // samples per thread-cell (32-aligned, never crosses a segment)
#define CPB    32                // cells per part (per head)
#define PART   (CELL * CPB)      // 1024 samples
#define NPARTS (NS / PART)       // 32 parts per sequence
#define TPB    256
#define NBATCH 16
#define GRID   (NBATCH * NPARTS) // 512 blocks = 2 blocks/CU on 256 CUs (co-resident)
#define NBIN   6                 // bins spanned by one part (4 segments + edges)

// sin(2*pi*x): v_sin_f32 takes revolutions; reduce to [-0.5, 0.5] first
__device__ __forceinline__ float sinr(float x) {
    return __builtin_amdgcn_sinf(x - rintf(x));
}

// linear-interp segment params for a 32-aligned cell at sample i
__device__ __forceinline__ void seg_params(int i, int& lo, int& hi,
                                           double& w0, double& wst) {
    if (i < 128)            { lo = 0;   hi = 1;   w0 = 0.0; wst = 0.0; }
    else if (i >= NS - 128) { lo = 127; hi = 127; w0 = 0.0; wst = 0.0; }
    else {
        lo = (i - 128) >> 8;  hi = lo + 1;
        int off = (i - 128) & 255;
        w0 = (off + 0.5) * (1.0 / 256.0);
        wst = 1.0 / 256.0;
    }
}

// bin value for stream q at bin j; phase streams (f0, std, modf) and b are
// pre-scaled to revolutions so all downstream phase math is in revolutions
__device__ __forceinline__ double bin_value(const float* xs, int q, int j) {
    const double PI_    = 3.14159265358979323846;
    const double INV2PI = 0.15915494309189533576888376337251;
    const double MINF   = 40.0 / 11025.0;
    const double FRNG   = (4000.0 - 40.0) / 11025.0;
    if (q == 0) {                                   // amp (unscaled)
        double a0 = (double)xs[j], a1 = (double)xs[NB + j];
        return sqrt(a0 * a0 + a1 * a1);
    }
    double ang = atan2((double)xs[(2 * q - 1) * NB + j],
                       (double)xs[(2 * q - 2) * NB + j]) / PI_;
    double sh, sc;
    if      (q == 1) { sh = MINF; sc = FRNG; }      // f0
    else if (q == 2) { sh = 1.0;  sc = 0.5;  }      // mix (amplitude, unscaled)
    else if (q == 3) { sh = MINF; sc = FRNG; }      // noise_std
    else if (q == 4) { sh = 0.25; sc = 4.75; }      // mod_factor
    else             { sh = 0.1;  sc = 9.9;  }      // b
    double v = sh + ang * sc;
    if (q != 2) v *= INV2PI;
    return v;
}

// closed-form f64 cell totals over 32 samples; S0/S1 summed in f32 (error
// ~1e-8 rev per cell — far below the f32 synth noise floor)
__device__ __forceinline__ void cell_totals(
        const float4 (&nn)[CELL / 4], double f0L, double dF0, double stL,
        double dSt, double mfL, double dMf, double w0, double wst,
        double& t1, double& t3, double& t2) {
    float s0 = 0.f, s1 = 0.f;
    #pragma unroll
    for (int q4 = 0; q4 < CELL / 4; ++q4) {
        float4 nv = nn[q4];
        float jd = (float)(q4 * 4);
        s0 += nv.x; s1 = fmaf(jd, nv.x, s1);
        s0 += nv.y; s1 = fmaf(jd + 1.f, nv.y, s1);
        s0 += nv.z; s1 = fmaf(jd + 2.f, nv.z, s1);
        s0 += nv.w; s1 = fmaf(jd + 3.f, nv.w, s1);
    }
    double S0 = (double)s0, S1 = (double)s1;
    double sw = 32.0 * w0 + 496.0 * wst;            // sum of w over the cell
    t3 = 32.0 * f0L + dF0 * sw;
    t2 = 32.0 * mfL + dMf * sw;
    t1 = t3 + stL * S0 + dSt * (w0 * S0 + wst * S1);
}

// ---- fused kernel: one noise read, one scan, grid-wide sync for the
// cross-part prefix. Unified thread layout = old K2's (h in lane bits 0..2
// for the head-mean butterfly; stride-8 in-part scan). The per-part span
// total is just (b + v) at the last cell, so old K1 is fully subsumed.
__global__ __launch_bounds__(TPB, 2)
void fused_kernel(const float* __restrict__ xg, const float* __restrict__ ng,
                  double* __restrict__ wspan, float* __restrict__ out) {
    __shared__ double binsA[8][3][NBIN];   // f0, std, modf (f64, for exact prefix)
    __shared__ float  binsB[8][6][NBIN];   // all 6 streams (f32, for synth)
    __shared__ double wtot[4][8][3];
    __shared__ double prefL[8][3];

    int bx = blockIdx.x, bb = bx >> 5, p = bx & (NPARTS - 1);
    int tid = threadIdx.x, lane = tid & 63, wid = tid >> 6;
    int h = tid & 7, c = tid >> 3;         // butterfly needs h in lane bits 0..2
    int P = p * PART;
    int b0 = (P - 128) >> 8; if (b0 < 0) b0 = 0;
    int s  = (bb << 3) + h;
    int i0 = P + c * CELL;

    // stage bins once: 8 heads x 6 streams x NBIN
    for (int idx = tid; idx < 8 * 6 * NBIN; idx += TPB) {
        int j = idx % NBIN, q = (idx / NBIN) % 6, h2 = idx / (6 * NBIN);
        const float* xs = xg + (size_t)((bb << 3) + h2) * 10 * NB;
        double v = bin_value(xs, q, min(b0 + j, NB - 1));
        binsB[h2][q][j] = (float)v;
        if      (q == 1) binsA[h2][0][j] = v;
        else if (q == 3) binsA[h2][1][j] = v;
        else if (q == 4) binsA[h2][2][j] = v;
    }
    __syncthreads();

    int lo, hi; double w0, wst;
    seg_params(i0, lo, hi, w0, wst);
    int jL = lo - b0, jH = hi - b0;

    // noise: load ONCE into registers, reuse in the synth phase
    const float4* np_ = reinterpret_cast<const float4*>(ng + (size_t)s * NS + i0);
    float4 nv[CELL / 4];
    #pragma unroll
    for (int q4 = 0; q4 < CELL / 4; ++q4) nv[q4] = np_[q4];

    double t1, t3, t2;
    {   // f64 bin regs die after cell_totals (keeps live set small across grid sync)
        double f0L = binsA[h][0][jL], dF0 = binsA[h][0][jH] - f0L;
        double stL = binsA[h][1][jL], dSt = binsA[h][1][jH] - stL;
        double mfL = binsA[h][2][jL], dMf = binsA[h][2][jH] - mfL;
        cell_totals(nv, f0L, dF0, stL, dSt, mfL, dMf, w0, wst, t1, t3, t2);
    }

    // in-part scan: stride-8 wave scan (head lane fixed) + cross-wave combine
    double v1 = t1, v3 = t3, v2 = t2;
    #pragma unroll
    for (int d = 8; d < 64; d <<= 1) {
        double u1 = __shfl_up(v1, d);
        double u3 = __shfl_up(v3, d);
        double u2 = __shfl_up(v2, d);
        if (lane >= d) { v1 += u1; v3 += u3; v2 += u2; }
    }
    if (lane >= 56) { wtot[wid][h][0] = v1; wtot[wid][h][1] = v3; wtot[wid][h][2] = v2; }
    __syncthreads();
    double b1 = 0.0, b3 = 0.0, b2 = 0.0;
    #pragma unroll
    for (int k = 0; k < 3; ++k)
        if (wid > k) { b1 += wtot[k][h][0]; b3 += wtot[k][h][1]; b2 += wtot[k][h][2]; }

    // part total = inclusive value at the last cell (wid 3, lane 56+h)
    if (wid == 3 && lane >= 56) {
        size_t sb = ((size_t)s * NPARTS + p) * 3;
        wspan[sb + 0] = b1 + v1; wspan[sb + 1] = b3 + v3; wspan[sb + 2] = b2 + v2;
    }

    cg::this_grid().sync();   // all 512 blocks co-resident (2/CU, VGPR<=256 via launch_bounds)

    // cross-part prefix: 24 chains (8h x 3k) x 8 threads, <=4 strided loads each
    if (tid < 192) {          // waves 0..2 fully active -> shuffle-safe
        int r = tid & 7, g = tid >> 3, k = g % 3, h2 = g / 3;
        const double* sp = wspan + ((size_t)(((bb << 3) + h2) * NPARTS)) * 3 + k;
        double acc = 0.0;
        #pragma unroll
        for (int q = 0; q < NPARTS / 8; ++q) {
            int idx = r + q * 8;
            if (idx < p) acc += sp[idx * 3];
        }
        #pragma unroll
        for (int m = 1; m <= 4; m <<= 1) acc += __shfl_xor(acc, m);
        if (r == 0) prefL[h2][k] = acc;
    }
    __syncthreads();

    // exact f64 anchors -> f32 fractional revolutions
    double a1 = prefL[h][0] + b1 + (v1 - t1);
    double a3 = prefL[h][1] + b3 + (v3 - t3);
    double a2 = prefL[h][2] + b2 + (v2 - t2);
    float fr1 = (float)(a1 - rint(a1));
    float fr3 = (float)(a3 - rint(a3));
    float fr2 = (float)(a2 - rint(a2));

    float amL = binsB[h][0][jL], dAm = binsB[h][0][jH] - amL;
    float g0L = binsB[h][1][jL], gF0 = binsB[h][1][jH] - g0L;
    float mxL = binsB[h][2][jL], dMx = binsB[h][2][jH] - mxL;
    float gsL = binsB[h][3][jL], gSt = binsB[h][3][jH] - gsL;
    float gmL = binsB[h][4][jL], gMf = binsB[h][4][jH] - gmL;
    float bbL = binsB[h][5][jL], dBb = binsB[h][5][jH] - bbL;
    float w0f = (float)w0, wsf = (float)wst;

    float arr[CELL];
    float d1 = 0.f, d2 = 0.f, d3 = 0.f;
    #pragma unroll
    for (int q4 = 0; q4 < CELL / 4; ++q4) {
        float nf[4] = {nv[q4].x, nv[q4].y, nv[q4].z, nv[q4].w};  // register-resident
        #pragma unroll
        for (int u = 0; u < 4; ++u) {
            int j = q4 * 4 + u;
            float wf  = fmaf((float)j, wsf, w0f);
            float f0v = fmaf(wf, gF0, g0L);
            float stv = fmaf(wf, gSt, gsL);
            float mfv = fmaf(wf, gMf, gmL);
            d3 += f0v;                       // cs3 (rev, relative to anchor)
            d1 += fmaf(nf[u], stv, f0v);     // cs1
            d2 += mfv;                       // cs2
            float ampv = fmaf(wf, dAm, amL);
            float mixv = fmaf(wf, dMx, mxL);
            float bv   = fmaf(wf, dBb, bbL);
            float s2 = sinr(fr2 + d2);
            float s1 = sinr(fr1 + d1);
            float s3 = sinr(fmaf(bv, s2, fr3 + d3));
            float harm = ampv * mixv;
            arr[j] = fmaf(harm, s3, (ampv - harm) * s1);
        }
    }

    // head-mean: butterfly over lane bits 0..2
    #pragma unroll
    for (int m = 1; m <= 4; m <<= 1) {
        #pragma unroll
        for (int j = 0; j < CELL; ++j) arr[j] += __shfl_xor(arr[j], m);
    }
    if (h == 0) {
        float4* op = reinterpret_cast<float4*>(out + (size_t)bb * NS + i0);
        #pragma unroll
        for (int j4 = 0; j4 < CELL / 4; ++j4)
            op[j4] = make_float4(arr[j4 * 4 + 0] * 0.125f, arr[j4 * 4 + 1] * 0.125f,
                                 arr[j4 * 4 + 2] * 0.125f, arr[j4 * 4 + 3] * 0.125f);
    }
}

// ---------------- fallback: proven 2-kernel path (if coop launch rejected) ----
__global__ __launch_bounds__(TPB)
void span_kernel(const float* __restrict__ xg, const float* __restrict__ ng,
                 double* __restrict__ wspan) {
    __shared__ double binsA[8][3][NBIN];

    int bx = blockIdx.x, bb = bx >> 5, p = bx & (NPARTS - 1);
    int tid = threadIdx.x, lane = tid & 63;
    int h = tid >> 5, c = tid & 31;
    int P = p * PART;
    int b0 = (P - 128) >> 8; if (b0 < 0) b0 = 0;
    int s  = (bb << 3) + h;
    int i0 = P + c * CELL;

    if (tid < 144) {
        int j = tid % NBIN, r = (tid / NBIN) % 3, h2 = tid / (3 * NBIN);
        int q = (r == 0) ? 1 : (r == 1) ? 3 : 4;
        const float* xs = xg + (size_t)((bb << 3) + h2) * 10 * NB;
        binsA[h2][r][j] = bin_value(xs, q, min(b0 + j, NB - 1));
    }
    __syncthreads();

    int lo, hi; double w0, wst;
    seg_params(i0, lo, hi, w0, wst);
    int jL = lo - b0, jH = hi - b0;
    double f0L = binsA[h][0][jL], dF0 = binsA[h][0][jH] - f0L;
    double stL = binsA[h][1][jL], dSt = binsA[h][1][jH] - stL;
    double mfL = binsA[h][2][jL], dMf = binsA[h][2][jH] - mfL;

    const float4* np_ = reinterpret_cast<const float4*>(ng + (size_t)s * NS + i0);
    float4 nv[CELL / 4];
    #pragma unroll
    for (int q4 = 0; q4 < CELL / 4; ++q4) nv[q4] = np_[q4];
    double t1, t3, t2;
    cell_totals(nv, f0L, dF0, stL, dSt, mfL, dMf, w0, wst, t1, t3, t2);

    double v1 = t1, v3 = t3, v2 = t2;
    #pragma unroll
    for (int d = 1; d < 32; d <<= 1) {
        double u1 = __shfl_up(v1, d);
        double u3 = __shfl_up(v3, d);
        double u2 = __shfl_up(v2, d);
        if ((lane & 31) >= d) { v1 += u1; v3 += u3; v2 += u2; }
    }
    if (c == 31) {
        size_t sb = ((size_t)s * NPARTS + p) * 3;
        wspan[sb + 0] = v1; wspan[sb + 1] = v3; wspan[sb + 2] = v2;
    }
}

__global__ __launch_bounds__(TPB)
void fm_kernel(const float* __restrict__ xg, const float* __restrict__ ng,
               const double* __restrict__ wspan, float* __restrict__ out) {
    __shared__ double binsA[8][3][NBIN];
    __shared__ float  binsB[8][6][NBIN];
    __shared__ double wtot[4][8][3];
    __shared__ double prefL[8][3];

    int bx = blockIdx.x, bb = bx >> 5, p = bx & (NPARTS - 1);
    int tid = threadIdx.x, lane = tid & 63, wid = tid >> 6;
    int h = tid & 7, c = tid >> 3;
    int P = p * PART;
    int b0 = (P - 128) >> 8; if (b0 < 0) b0 = 0;
    int s  = (bb << 3) + h;
    int i0 = P + c * CELL;

    if (tid < 192) {
        int r = tid & 7, g = tid >> 3, k = g % 3, h2 = g / 3;
        const double* sp = wspan + ((size_t)(((bb << 3) + h2) * NPARTS)) * 3 + k;
        double acc = 0.0;
        #pragma unroll
        for (int q = 0; q < NPARTS / 8; ++q) {
            int idx = r + q * 8;
            if (idx < p) acc += sp[idx * 3];
        }
        #pragma unroll
        for (int m = 1; m <= 4; m <<= 1) acc += __shfl_xor(acc, m);
        if (r == 0) prefL[h2][k] = acc;
    }
    for (int idx = tid; idx < 8 * 6 * NBIN; idx += TPB) {
        int j = idx % NBIN, q = (idx / NBIN) % 6, h2 = idx / (6 * NBIN);
        const float* xs = xg + (size_t)((bb << 3) + h2) * 10 * NB;
        double v = bin_value(xs, q, min(b0 + j, NB - 1));
        binsB[h2][q][j] = (float)v;
        if      (q == 1) binsA[h2][0][j] = v;
        else if (q == 3) binsA[h2][1][j] = v;
        else if (q == 4) binsA[h2][2][j] = v;
    }
    __syncthreads();

    int lo, hi; double w0, wst;
    seg_params(i0, lo, hi, w0, wst);
    int jL = lo - b0, jH = hi - b0;
    double f0L = binsA[h][0][jL], dF0 = binsA[h][0][jH] - f0L;
    double stL = binsA[h][1][jL], dSt = binsA[h][1][jH] - stL;
    double mfL = binsA[h][2][jL], dMf = binsA[h][2][jH] - mfL;

    const float4* np_ = reinterpret_cast<const float4*>(ng + (size_t)s * NS + i0);
    float4 nv[CELL / 4];
    #pragma unroll
    for (int q4 = 0; q4 < CELL / 4; ++q4) nv[q4] = np_[q4];
    double t1, t3, t2;
    cell_totals(nv, f0L, dF0, stL, dSt, mfL, dMf, w0, wst, t1, t3, t2);

    double v1 = t1, v3 = t3, v2 = t2;
    #pragma unroll
    for (int d = 8; d < 64; d <<= 1) {
        double u1 = __shfl_up(v1, d);
        double u3 = __shfl_up(v3, d);
        double u2 = __shfl_up(v2, d);
        if (lane >= d) { v1 += u1; v3 += u3; v2 += u2; }
    }
    if (lane >= 56) { wtot[wid][h][0] = v1; wtot[wid][h][1] = v3; wtot[wid][h][2] = v2; }
    __syncthreads();
    double b1 = 0.0, b3 = 0.0, b2 = 0.0;
    #pragma unroll
    for (int k = 0; k < 3; ++k)
        if (wid > k) { b1 += wtot[k][h][0]; b3 += wtot[k][h][1]; b2 += wtot[k][h][2]; }

    double a1 = prefL[h][0] + b1 + (v1 - t1);
    double a3 = prefL[h][1] + b3 + (v3 - t3);
    double a2 = prefL[h][2] + b2 + (v2 - t2);
    float fr1 = (float)(a1 - rint(a1));
    float fr3 = (float)(a3 - rint(a3));
    float fr2 = (float)(a2 - rint(a2));

    float amL = binsB[h][0][jL], dAm = binsB[h][0][jH] - amL;
    float g0L = binsB[h][1][jL], gF0 = binsB[h][1][jH] - g0L;
    float mxL = binsB[h][2][jL], dMx = binsB[h][2][jH] - mxL;
    float gsL = binsB[h][3][jL], gSt = binsB[h][3][jH] - gsL;
    float gmL = binsB[h][4][jL], gMf = binsB[h][4][jH] - gmL;
    float bbL = binsB[h][5][jL], dBb = binsB[h][5][jH] - bbL;
    float w0f = (float)w0, wsf = (float)wst;

    float arr[CELL];
    float d1 = 0.f, d2 = 0.f, d3 = 0.f;
    #pragma unroll
    for (int q4 = 0; q4 < CELL / 4; ++q4) {
        float nf[4] = {nv[q4].x, nv[q4].y, nv[q4].z, nv[q4].w};
        #pragma unroll
        for (int u = 0; u < 4; ++u) {
            int j = q4 * 4 + u;
            float wf  = fmaf((float)j, wsf, w0f);
            float f0v = fmaf(wf, gF0, g0L);
            float stv = fmaf(wf, gSt, gsL);
            float mfv = fmaf(wf, gMf, gmL);
            d3 += f0v;
            d1 += fmaf(nf[u], stv, f0v);
            d2 += mfv;
            float ampv = fmaf(wf, dAm, amL);
            float mixv = fmaf(wf, dMx, mxL);
            float bv   = fmaf(wf, dBb, bbL);
            float s2 = sinr(fr2 + d2);
            float s1 = sinr(fr1 + d1);
            float s3 = sinr(fmaf(bv, s2, fr3 + d3));
            float harm = ampv * mixv;
            arr[j] = fmaf(harm, s3, (ampv - harm) * s1);
        }
    }

    #pragma unroll
    for (int m = 1; m <= 4; m <<= 1) {
        #pragma unroll
        for (int j = 0; j < CELL; ++j) arr[j] += __shfl_xor(arr[j], m);
    }
    if (h == 0) {
        float4* op = reinterpret_cast<float4*>(out + (size_t)bb * NS + i0);
        #pragma unroll
        for (int j4 = 0; j4 < CELL / 4; ++j4)
            op[j4] = make_float4(arr[j4 * 4 + 0] * 0.125f, arr[j4 * 4 + 1] * 0.125f,
                                 arr[j4 * 4 + 2] * 0.125f, arr[j4 * 4 + 3] * 0.125f);
    }
}

extern "C" void kernel_launch(void* const* d_in, const int* in_sizes, int n_in,
                              void* d_out, int out_size, void* d_ws, size_t ws_size,
                              hipStream_t stream) {
    const float* x     = (const float*)d_in[0];
    const float* noise = (const float*)d_in[1];
    float* out = (float*)d_out;
    double* wspan = (double*)d_ws;   // [128 seq][32 part][3] f64 = 98304 B
    void* args[] = { (void*)&x, (void*)&noise, (void*)&wspan, (void*)&out };
    hipError_t err = hipLaunchCooperativeKernel(
        reinterpret_cast<void*>(fused_kernel), dim3(GRID), dim3(TPB),
        args, 0, stream);
    if (err != hipSuccess) {
        // cooperative path unavailable: proven 2-kernel fallback
        span_kernel<<<GRID, TPB, 0, stream>>>(x, noise, wspan);
        fm_kernel<<<GRID, TPB, 0, stream>>>(x, noise, wspan, out);
    }
}

// Round 2
// 85.028 us; speedup vs baseline: 1.6522x; 1.6522x over previous
//
#include <hip/hip_runtime.h>
#include <math.h>

#define NS     32768             // samples per sequence
#define NB     128               // interpolation bins
#define CELL   8                 // samples per thread-cell (8-aligned, never crosses a segment)
#define CPB    32                // cells per part (per head)
#define PART   (CELL * CPB)      // 256 samples
#define NPARTS (NS / PART)       // 128 parts per sequence
#define TPB    256
#define NBATCH 16
#define GRID   (NBATCH * NPARTS) // 2048 blocks = 8 blocks/CU -> up to 32 waves/CU
#define NBIN   3                 // bins spanned by one 256-sample part
#define SJ     ((CELL * (CELL - 1)) / 2)   // sum of j over a cell = 28

// sin(2*pi*x): v_sin_f32 takes revolutions; reduce to [-0.5, 0.5] first
__device__ __forceinline__ float sinr(float x) {
    return __builtin_amdgcn_sinf(x - rintf(x));
}

// linear-interp segment params for an 8-aligned cell at sample i
// (segment boundaries at 128 + 256k are multiples of 8 -> no cell straddles)
__device__ __forceinline__ void seg_params(int i, int& lo, int& hi,
                                           double& w0, double& wst) {
    if (i < 128)            { lo = 0;   hi = 1;   w0 = 0.0; wst = 0.0; }
    else if (i >= NS - 128) { lo = 127; hi = 127; w0 = 0.0; wst = 0.0; }
    else {
        lo = (i - 128) >> 8;  hi = lo + 1;
        int off = (i - 128) & 255;
        w0 = (off + 0.5) * (1.0 / 256.0);
        wst = 1.0 / 256.0;
    }
}

// bin value for stream q at bin j; phase streams (f0, std, modf) and b are
// pre-scaled to revolutions so all downstream phase math is in revolutions
__device__ __forceinline__ double bin_value(const float* xs, int q, int j) {
    const double PI_    = 3.14159265358979323846;
    const double INV2PI = 0.15915494309189533576888376337251;
    const double MINF   = 40.0 / 11025.0;
    const double FRNG   = (4000.0 - 40.0) / 11025.0;
    if (q == 0) {                                   // amp (unscaled)
        double a0 = (double)xs[j], a1 = (double)xs[NB + j];
        return sqrt(a0 * a0 + a1 * a1);
    }
    double ang = atan2((double)xs[(2 * q - 1) * NB + j],
                       (double)xs[(2 * q - 2) * NB + j]) / PI_;
    double sh, sc;
    if      (q == 1) { sh = MINF; sc = FRNG; }      // f0
    else if (q == 2) { sh = 1.0;  sc = 0.5;  }      // mix (amplitude, unscaled)
    else if (q == 3) { sh = MINF; sc = FRNG; }      // noise_std
    else if (q == 4) { sh = 0.25; sc = 4.75; }      // mod_factor
    else             { sh = 0.1;  sc = 9.9;  }      // b
    double v = sh + ang * sc;
    if (q != 2) v *= INV2PI;
    return v;
}

// closed-form f64 cell totals over CELL samples; S0/S1 summed in f32
// (error far below the f32 synth noise floor)
__device__ __forceinline__ void cell_totals(
        const float4 (&nn)[CELL / 4], double f0L, double dF0, double stL,
        double dSt, double mfL, double dMf, double w0, double wst,
        double& t1, double& t3, double& t2) {
    float s0 = 0.f, s1 = 0.f;
    #pragma unroll
    for (int q4 = 0; q4 < CELL / 4; ++q4) {
        float4 nv = nn[q4];
        float jd = (float)(q4 * 4);
        s0 += nv.x; s1 = fmaf(jd, nv.x, s1);
        s0 += nv.y; s1 = fmaf(jd + 1.f, nv.y, s1);
        s0 += nv.z; s1 = fmaf(jd + 2.f, nv.z, s1);
        s0 += nv.w; s1 = fmaf(jd + 3.f, nv.w, s1);
    }
    double S0 = (double)s0, S1 = (double)s1;
    double sw = (double)CELL * w0 + (double)SJ * wst;   // sum of w over the cell
    t3 = (double)CELL * f0L + dF0 * sw;
    t2 = (double)CELL * mfL + dMf * sw;
    t1 = t3 + stL * S0 + dSt * (w0 * S0 + wst * S1);
}

// ---- K1: per-(seq, part) span totals {cs1, cs3, cs2} -> wspan[seq][part][3]
// Layout h = tid>>5: half-wave per head -> coalesced loads, in-half-wave scan.
__global__ __launch_bounds__(TPB, 4)
void span_kernel(const float* __restrict__ xg, const float* __restrict__ ng,
                 double* __restrict__ wspan) {
    __shared__ double binsA[8][3][NBIN];   // f0, std, modf @ bins b0..b0+2

    int bx = blockIdx.x, bb = bx >> 7, p = bx & (NPARTS - 1);
    int tid = threadIdx.x, lane = tid & 63;
    int h = tid >> 5, c = tid & 31;
    int P = p * PART;
    int b0 = (P - 128) >> 8; if (b0 < 0) b0 = 0;
    int s  = (bb << 3) + h;
    int i0 = P + c * CELL;

    // hoist noise loads: independent of LDS staging -> HBM latency hides
    // under the f64 atan2 bin work
    const float4* np_ = reinterpret_cast<const float4*>(ng + (size_t)s * NS + i0);
    float4 nv[CELL / 4];
    #pragma unroll
    for (int q4 = 0; q4 < CELL / 4; ++q4) nv[q4] = np_[q4];

    if (tid < 8 * 3 * NBIN) {              // 8 heads x 3 streams x 3 bins = 72
        int j = tid % NBIN, r = (tid / NBIN) % 3, h2 = tid / (3 * NBIN);
        int q = (r == 0) ? 1 : (r == 1) ? 3 : 4;
        const float* xs = xg + (size_t)((bb << 3) + h2) * 10 * NB;
        binsA[h2][r][j] = bin_value(xs, q, min(b0 + j, NB - 1));
    }
    __syncthreads();

    int lo, hi; double w0, wst;
    seg_params(i0, lo, hi, w0, wst);
    int jL = lo - b0, jH = hi - b0;
    double f0L = binsA[h][0][jL], dF0 = binsA[h][0][jH] - f0L;
    double stL = binsA[h][1][jL], dSt = binsA[h][1][jH] - stL;
    double mfL = binsA[h][2][jL], dMf = binsA[h][2][jH] - mfL;

    double t1, t3, t2;
    cell_totals(nv, f0L, dF0, stL, dSt, mfL, dMf, w0, wst, t1, t3, t2);

    // inclusive scan over the 32 cells of this head (within the half-wave)
    double v1 = t1, v3 = t3, v2 = t2;
    #pragma unroll
    for (int d = 1; d < 32; d <<= 1) {
        double u1 = __shfl_up(v1, d);
        double u3 = __shfl_up(v3, d);
        double u2 = __shfl_up(v2, d);
        if ((lane & 31) >= d) { v1 += u1; v3 += u3; v2 += u2; }
    }
    if (c == 31) {
        size_t sb = ((size_t)s * NPARTS + p) * 3;
        wspan[sb + 0] = v1; wspan[sb + 1] = v3; wspan[sb + 2] = v2;
    }
}

// ---- K2: full synth; in-part prefix from own scan, cross-part from wspan
__global__ __launch_bounds__(TPB, 4)
void fm_kernel(const float* __restrict__ xg, const float* __restrict__ ng,
               const double* __restrict__ wspan, float* __restrict__ out) {
    __shared__ double binsA[8][3][NBIN];
    __shared__ float  binsB[8][6][NBIN];
    __shared__ double wtot[4][8][3];
    __shared__ double prefL[8][3];

    int bx = blockIdx.x, bb = bx >> 7, p = bx & (NPARTS - 1);
    int tid = threadIdx.x, lane = tid & 63, wid = tid >> 6;
    int h = tid & 7, c = tid >> 3;         // butterfly needs h in lane bits 0..2
    int P = p * PART;
    int b0 = (P - 128) >> 8; if (b0 < 0) b0 = 0;
    int s  = (bb << 3) + h;
    int i0 = P + c * CELL;

    // hoist noise loads before all LDS staging (latency overlap)
    const float4* np_ = reinterpret_cast<const float4*>(ng + (size_t)s * NS + i0);
    float4 nv[CELL / 4];
    #pragma unroll
    for (int q4 = 0; q4 < CELL / 4; ++q4) nv[q4] = np_[q4];

    // cross-part prefix: 24 chains (8h x 3k) x 8 threads, <=16 strided loads each
    if (tid < 192) {
        int r = tid & 7, g = tid >> 3, k = g % 3, h2 = g / 3;
        const double* sp = wspan + ((size_t)(((bb << 3) + h2) * NPARTS)) * 3 + k;
        double acc = 0.0;
        #pragma unroll
        for (int q = 0; q < NPARTS / 8; ++q) {
            int idx = r + q * 8;
            if (idx < p) acc += sp[idx * 3];
        }
        #pragma unroll
        for (int m = 1; m <= 4; m <<= 1) acc += __shfl_xor(acc, m);
        if (r == 0) prefL[h2][k] = acc;
    }
    // stage bins: 8 heads x 6 streams x 3 bins = 144 values
    if (tid < 8 * 6 * NBIN) {
        int j = tid % NBIN, q = (tid / NBIN) % 6, h2 = tid / (6 * NBIN);
        const float* xs = xg + (size_t)((bb << 3) + h2) * 10 * NB;
        double v = bin_value(xs, q, min(b0 + j, NB - 1));
        binsB[h2][q][j] = (float)v;
        if      (q == 1) binsA[h2][0][j] = v;
        else if (q == 3) binsA[h2][1][j] = v;
        else if (q == 4) binsA[h2][2][j] = v;
    }
    __syncthreads();

    int lo, hi; double w0, wst;
    seg_params(i0, lo, hi, w0, wst);
    int jL = lo - b0, jH = hi - b0;

    double t1, t3, t2;
    {
        double f0L = binsA[h][0][jL], dF0 = binsA[h][0][jH] - f0L;
        double stL = binsA[h][1][jL], dSt = binsA[h][1][jH] - stL;
        double mfL = binsA[h][2][jL], dMf = binsA[h][2][jH] - mfL;
        cell_totals(nv, f0L, dF0, stL, dSt, mfL, dMf, w0, wst, t1, t3, t2);
    }

    // in-part scan: stride-8 wave scan (head lane fixed) + cross-wave combine
    double v1 = t1, v3 = t3, v2 = t2;
    #pragma unroll
    for (int d = 8; d < 64; d <<= 1) {
        double u1 = __shfl_up(v1, d);
        double u3 = __shfl_up(v3, d);
        double u2 = __shfl_up(v2, d);
        if (lane >= d) { v1 += u1; v3 += u3; v2 += u2; }
    }
    if (lane >= 56) { wtot[wid][h][0] = v1; wtot[wid][h][1] = v3; wtot[wid][h][2] = v2; }
    __syncthreads();
    double b1 = 0.0, b3 = 0.0, b2 = 0.0;
    #pragma unroll
    for (int k = 0; k < 3; ++k)
        if (wid > k) { b1 += wtot[k][h][0]; b3 += wtot[k][h][1]; b2 += wtot[k][h][2]; }

    // exact f64 anchors -> f32 fractional revolutions
    double a1 = prefL[h][0] + b1 + (v1 - t1);
    double a3 = prefL[h][1] + b3 + (v3 - t3);
    double a2 = prefL[h][2] + b2 + (v2 - t2);
    float fr1 = (float)(a1 - rint(a1));
    float fr3 = (float)(a3 - rint(a3));
    float fr2 = (float)(a2 - rint(a2));

    float amL = binsB[h][0][jL], dAm = binsB[h][0][jH] - amL;
    float g0L = binsB[h][1][jL], gF0 = binsB[h][1][jH] - g0L;
    float mxL = binsB[h][2][jL], dMx = binsB[h][2][jH] - mxL;
    float gsL = binsB[h][3][jL], gSt = binsB[h][3][jH] - gsL;
    float gmL = binsB[h][4][jL], gMf = binsB[h][4][jH] - gmL;
    float bbL = binsB[h][5][jL], dBb = binsB[h][5][jH] - bbL;
    float w0f = (float)w0, wsf = (float)wst;

    float arr[CELL];
    float d1 = 0.f, d2 = 0.f, d3 = 0.f;
    #pragma unroll
    for (int q4 = 0; q4 < CELL / 4; ++q4) {
        float nf[4] = {nv[q4].x, nv[q4].y, nv[q4].z, nv[q4].w};  // register-resident
        #pragma unroll
        for (int u = 0; u < 4; ++u) {
            int j = q4 * 4 + u;
            float wf  = fmaf((float)j, wsf, w0f);
            float f0v = fmaf(wf, gF0, g0L);
            float stv = fmaf(wf, gSt, gsL);
            float mfv = fmaf(wf, gMf, gmL);
            d3 += f0v;                       // cs3 (rev, relative to anchor)
            d1 += fmaf(nf[u], stv, f0v);     // cs1
            d2 += mfv;                       // cs2
            float ampv = fmaf(wf, dAm, amL);
            float mixv = fmaf(wf, dMx, mxL);
            float bv   = fmaf(wf, dBb, bbL);
            float s2 = sinr(fr2 + d2);
            float s1 = sinr(fr1 + d1);
            float s3 = sinr(fmaf(bv, s2, fr3 + d3));
            float harm = ampv * mixv;
            arr[j] = fmaf(harm, s3, (ampv - harm) * s1);
        }
    }

    // head-mean: butterfly over lane bits 0..2
    #pragma unroll
    for (int m = 1; m <= 4; m <<= 1) {
        #pragma unroll
        for (int j = 0; j < CELL; ++j) arr[j] += __shfl_xor(arr[j], m);
    }
    if (h == 0) {
        float4* op = reinterpret_cast<float4*>(out + (size_t)bb * NS + i0);
        #pragma unroll
        for (int j4 = 0; j4 < CELL / 4; ++j4)
            op[j4] = make_float4(arr[j4 * 4 + 0] * 0.125f, arr[j4 * 4 + 1] * 0.125f,
                                 arr[j4 * 4 + 2] * 0.125f, arr[j4 * 4 + 3] * 0.125f);
    }
}

extern "C" void kernel_launch(void* const* d_in, const int* in_sizes, int n_in,
                              void* d_out, int out_size, void* d_ws, size_t ws_size,
                              hipStream_t stream) {
    const float* x     = (const float*)d_in[0];
    const float* noise = (const float*)d_in[1];
    float* out = (float*)d_out;
    double* wspan = (double*)d_ws;   // [128 seq][128 part][3] f64 = 393216 B
    span_kernel<<<GRID, TPB, 0, stream>>>(x, noise, wspan);
    fm_kernel<<<GRID, TPB, 0, stream>>>(x, noise, wspan, out);
}

// Round 3
// 81.574 us; speedup vs baseline: 1.7221x; 1.0423x over previous
//
#include <hip/hip_runtime.h>
#include <math.h>

#define NS      32768            // samples per sequence
#define NB      128              // interpolation bins
#define NSEQ    128              // 16 batch x 8 heads
#define NCHUNK  256              // 128-sample chunks per sequence
#define CHUNK   128
#define CELL    16               // samples per thread-cell in synth
#define PART    512              // samples per block per head (multiple of 256)
#define NPARTS  (NS / PART)      // 64
#define TPB     256
#define NBATCH  16
#define NBIN    4                // bins spanned by one 512-sample part
#define SJ      ((CELL * (CELL - 1)) / 2)   // 120

// sin(2*pi*x): v_sin_f32 takes revolutions; reduce to [-0.5, 0.5] first
__device__ __forceinline__ float sinr(float x) {
    return __builtin_amdgcn_sinf(x - rintf(x));
}

// f32 linear-interp segment params for a 16-aligned cell at sample i
// (segment boundaries 128+256k and flat-region edges are 16-aligned)
__device__ __forceinline__ void seg_params_f(int i, int& lo, int& hi,
                                             float& w0, float& wst) {
    if (i < 128)            { lo = 0;   hi = 1;   w0 = 0.f; wst = 0.f; }
    else if (i >= NS - 128) { lo = 127; hi = 127; w0 = 0.f; wst = 0.f; }
    else {
        lo = (i - 128) >> 8;  hi = lo + 1;
        int off = (i - 128) & 255;
        w0 = (float)(off + 0.5f) * (1.0f / 256.0f);
        wst = 1.0f / 256.0f;
    }
}

// bin value for stream q at bin j; phase streams (f0, std, modf) and b are
// pre-scaled to revolutions so all downstream phase math is in revolutions
__device__ __forceinline__ double bin_value(const float* xs, int q, int j) {
    const double PI_    = 3.14159265358979323846;
    const double INV2PI = 0.15915494309189533576888376337251;
    const double MINF   = 40.0 / 11025.0;
    const double FRNG   = (4000.0 - 40.0) / 11025.0;
    if (q == 0) {                                   // amp (unscaled)
        double a0 = (double)xs[j], a1 = (double)xs[NB + j];
        return sqrt(a0 * a0 + a1 * a1);
    }
    double ang = atan2((double)xs[(2 * q - 1) * NB + j],
                       (double)xs[(2 * q - 2) * NB + j]) / PI_;
    double sh, sc;
    if      (q == 1) { sh = MINF; sc = FRNG; }      // f0
    else if (q == 2) { sh = 1.0;  sc = 0.5;  }      // mix (amplitude, unscaled)
    else if (q == 3) { sh = MINF; sc = FRNG; }      // noise_std
    else if (q == 4) { sh = 0.25; sc = 4.75; }      // mod_factor
    else             { sh = 0.1;  sc = 9.9;  }      // b
    double v = sh + ang * sc;
    if (q != 2) v *= INV2PI;
    return v;
}

// ---- K1: per-(seq, chunk) noise sums S0 = sum(n), S1 = sum(j*n), j in [0,128)
// Pure streaming, fully coalesced: block = 1024 contiguous samples of one seq.
__global__ __launch_bounds__(TPB)
void sum_kernel(const float* __restrict__ ng, float* __restrict__ chunkS) {
    int bid = blockIdx.x;                 // 4096 = NSEQ * 32
    int seq = bid >> 5, blk = bid & 31;
    int t = threadIdx.x;
    int ck = t >> 5, l = t & 31;          // 8 chunks per block, 32 lanes each
    int base = blk * 1024 + ck * CHUNK + l * 4;
    const float4 nv = *reinterpret_cast<const float4*>(
        ng + (size_t)seq * NS + base);
    float j0 = (float)(l * 4);
    float s0 = nv.x + nv.y + nv.z + nv.w;
    float s1 = fmaf(j0, nv.x, fmaf(j0 + 1.f, nv.y,
               fmaf(j0 + 2.f, nv.z, (j0 + 3.f) * nv.w)));
    #pragma unroll
    for (int m = 1; m <= 16; m <<= 1) {
        s0 += __shfl_xor(s0, m);
        s1 += __shfl_xor(s1, m);
    }
    if (l == 0) {
        int chunk = blk * 8 + ck;
        float2* o = reinterpret_cast<float2*>(
            chunkS + ((size_t)seq * NCHUNK + chunk) * 2);
        *o = make_float2(s0, s1);
    }
}

// ---- K2: per-sequence bins (f32, once) + f64 closed-form chunk scan ->
// fractional f32 anchors at every part boundary. One block per sequence.
// Chunk c closed forms (chunks 1..254: segment k=(c-1)>>1, half hf=(c-1)&1):
//   sum(w) over chunk = 64*hf + 32 ;  sum(w*n) = ((128*hf+0.5)*S0 + S1)/256
__global__ __launch_bounds__(TPB)
void anchor_kernel(const float* __restrict__ xg, const float* __restrict__ chunkS,
                   float* __restrict__ binsG, float* __restrict__ frG) {
    __shared__ double bf[3][NB];     // f0, std, modf (revolutions, f64)
    __shared__ double wsum[4][3];

    int seq = blockIdx.x;            // 128
    int t = threadIdx.x;
    const float* xs = xg + (size_t)seq * 10 * NB;

    for (int idx = t; idx < 6 * NB; idx += TPB) {
        int q = idx >> 7, j = idx & (NB - 1);
        double v = bin_value(xs, q, j);
        binsG[((size_t)seq * 6 + q) * NB + j] = (float)v;
        if      (q == 1) bf[0][j] = v;
        else if (q == 3) bf[1][j] = v;
        else if (q == 4) bf[2][j] = v;
    }
    __syncthreads();

    int c = t;                       // thread c owns chunk c (0..255)
    float2 sv = *reinterpret_cast<const float2*>(
        chunkS + ((size_t)seq * NCHUNK + c) * 2);
    double S0 = (double)sv.x, S1 = (double)sv.y;
    double t1, t3, t2;
    if (c == 0) {                                    // flat head: value = bin 0
        t3 = 128.0 * bf[0][0];
        t2 = 128.0 * bf[2][0];
        t1 = t3 + bf[1][0] * S0;
    } else if (c == NCHUNK - 1) {                    // flat tail: value = bin 127
        t3 = 128.0 * bf[0][NB - 1];
        t2 = 128.0 * bf[2][NB - 1];
        t1 = t3 + bf[1][NB - 1] * S0;
    } else {
        int k = (c - 1) >> 1, hf = (c - 1) & 1;
        double sw  = 64.0 * (double)hf + 32.0;
        double f0L = bf[0][k], dF0 = bf[0][k + 1] - f0L;
        double stL = bf[1][k], dSt = bf[1][k + 1] - stL;
        double mfL = bf[2][k], dMf = bf[2][k + 1] - mfL;
        t3 = 128.0 * f0L + dF0 * sw;
        t2 = 128.0 * mfL + dMf * sw;
        t1 = t3 + stL * S0
                + dSt * ((128.0 * (double)hf + 0.5) * S0 + S1) * (1.0 / 256.0);
    }

    // inclusive scan over 256 chunks: in-wave + cross-wave combine
    int lane = t & 63, wid = t >> 6;
    double v1 = t1, v3 = t3, v2 = t2;
    #pragma unroll
    for (int d = 1; d < 64; d <<= 1) {
        double u1 = __shfl_up(v1, d);
        double u3 = __shfl_up(v3, d);
        double u2 = __shfl_up(v2, d);
        if (lane >= d) { v1 += u1; v3 += u3; v2 += u2; }
    }
    if (lane == 63) { wsum[wid][0] = v1; wsum[wid][1] = v3; wsum[wid][2] = v2; }
    __syncthreads();
    double b1 = 0.0, b3 = 0.0, b2 = 0.0;
    #pragma unroll
    for (int k = 0; k < 3; ++k)
        if (wid > k) { b1 += wsum[k][0]; b3 += wsum[k][1]; b2 += wsum[k][2]; }
    v1 += b1; v3 += b3; v2 += b2;

    // part p starts at chunk 4p -> anchor = inclusive prefix through chunk 4p-1
    if ((c & 3) == 3 && c < 4 * (NPARTS - 1)) {      // c = 3..251 -> p = 1..63
        int p = (c >> 2) + 1;
        float* o = frG + ((size_t)seq * NPARTS + p) * 3;
        o[0] = (float)(v1 - rint(v1));
        o[1] = (float)(v3 - rint(v3));
        o[2] = (float)(v2 - rint(v2));
    }
    if (c == 0) {                                    // p = 0 anchor is zero
        float* o = frG + (size_t)seq * NPARTS * 3;
        o[0] = 0.f; o[1] = 0.f; o[2] = 0.f;
    }
}

// ---- K3: synth. No f64, no atan2, no lookback: bins + fractional anchors
// come precomputed. In-part f32 scan (max ~370 rev -> ulp 3e-5, << tol).
__global__ __launch_bounds__(TPB, 4)
void fm_kernel(const float* __restrict__ ng, const float* __restrict__ binsG,
               const float* __restrict__ frG, float* __restrict__ out) {
    __shared__ float binsB[8][6][NBIN];
    __shared__ float frL[8][3];
    __shared__ float wtot[4][8][3];

    int bx = blockIdx.x;                  // 1024 = NBATCH * NPARTS
    int bb = bx >> 6, p = bx & (NPARTS - 1);
    int tid = threadIdx.x, lane = tid & 63, wid = tid >> 6;
    int h = tid & 7, c = tid >> 3;        // butterfly needs h in lane bits 0..2
    int P = p * PART;
    int b0 = (P - 128) >> 8; if (b0 < 0) b0 = 0;
    int s  = (bb << 3) + h;
    int i0 = P + c * CELL;

    // noise loads first: HBM latency hides under the (tiny) staging phase
    const float4* np_ = reinterpret_cast<const float4*>(ng + (size_t)s * NS + i0);
    float4 nv[CELL / 4];
    #pragma unroll
    for (int q4 = 0; q4 < CELL / 4; ++q4) nv[q4] = np_[q4];

    // stage f32 bins (8h x 6q x 4bins = 192) and anchors (8h x 3 = 24)
    if (tid < 192) {
        int j = tid & 3, q = (tid >> 2) % 6, h2 = tid / 24;
        binsB[h2][q][j] =
            binsG[((size_t)((bb << 3) + h2) * 6 + q) * NB + min(b0 + j, NB - 1)];
    }
    if (tid < 24) {
        int k = tid % 3, h2 = tid / 3;
        frL[h2][k] = frG[((size_t)((bb << 3) + h2) * NPARTS + p) * 3 + k];
    }
    __syncthreads();

    int lo, hi; float w0, wst;
    seg_params_f(i0, lo, hi, w0, wst);
    int jL = lo - b0, jH = hi - b0;

    float amL = binsB[h][0][jL], dAm = binsB[h][0][jH] - amL;
    float g0L = binsB[h][1][jL], gF0 = binsB[h][1][jH] - g0L;
    float mxL = binsB[h][2][jL], dMx = binsB[h][2][jH] - mxL;
    float gsL = binsB[h][3][jL], gSt = binsB[h][3][jH] - gsL;
    float gmL = binsB[h][4][jL], gMf = binsB[h][4][jH] - gmL;
    float bbL = binsB[h][5][jL], dBb = binsB[h][5][jH] - bbL;

    // f32 cell totals over CELL samples
    float s0 = 0.f, s1 = 0.f;
    #pragma unroll
    for (int q4 = 0; q4 < CELL / 4; ++q4) {
        float jd = (float)(q4 * 4);
        s0 += nv[q4].x; s1 = fmaf(jd,       nv[q4].x, s1);
        s0 += nv[q4].y; s1 = fmaf(jd + 1.f, nv[q4].y, s1);
        s0 += nv[q4].z; s1 = fmaf(jd + 2.f, nv[q4].z, s1);
        s0 += nv[q4].w; s1 = fmaf(jd + 3.f, nv[q4].w, s1);
    }
    float sw = (float)CELL * w0 + (float)SJ * wst;
    float t3 = (float)CELL * g0L + gF0 * sw;
    float t2 = (float)CELL * gmL + gMf * sw;
    float t1 = t3 + gsL * s0 + gSt * fmaf(w0, s0, wst * s1);

    // in-part scan: stride-8 wave scan (head lane fixed) + cross-wave combine
    float v1 = t1, v3 = t3, v2 = t2;
    #pragma unroll
    for (int d = 8; d < 64; d <<= 1) {
        float u1 = __shfl_up(v1, d);
        float u3 = __shfl_up(v3, d);
        float u2 = __shfl_up(v2, d);
        if (lane >= d) { v1 += u1; v3 += u3; v2 += u2; }
    }
    if (lane >= 56) { wtot[wid][h][0] = v1; wtot[wid][h][1] = v3; wtot[wid][h][2] = v2; }
    __syncthreads();
    float b1 = 0.f, b3 = 0.f, b2 = 0.f;
    #pragma unroll
    for (int k = 0; k < 3; ++k)
        if (wid > k) { b1 += wtot[k][h][0]; b3 += wtot[k][h][1]; b2 += wtot[k][h][2]; }

    // cell-start phases (anchor + exclusive in-part prefix), reduced mod 1
    float fr1 = frL[h][0] + b1 + (v1 - t1); fr1 -= rintf(fr1);
    float fr3 = frL[h][1] + b3 + (v3 - t3); fr3 -= rintf(fr3);
    float fr2 = frL[h][2] + b2 + (v2 - t2); fr2 -= rintf(fr2);

    float arr[CELL];
    float d1 = 0.f, d2 = 0.f, d3 = 0.f;
    #pragma unroll
    for (int q4 = 0; q4 < CELL / 4; ++q4) {
        float nf[4] = {nv[q4].x, nv[q4].y, nv[q4].z, nv[q4].w};
        #pragma unroll
        for (int u = 0; u < 4; ++u) {
            int j = q4 * 4 + u;
            float wf  = fmaf((float)j, wst, w0);
            float f0v = fmaf(wf, gF0, g0L);
            float stv = fmaf(wf, gSt, gsL);
            float mfv = fmaf(wf, gMf, gmL);
            d3 += f0v;                       // cs3 (rev, relative to anchor)
            d1 += fmaf(nf[u], stv, f0v);     // cs1
            d2 += mfv;                       // cs2
            float ampv = fmaf(wf, dAm, amL);
            float mixv = fmaf(wf, dMx, mxL);
            float bv   = fmaf(wf, dBb, bbL);
            float s2 = sinr(fr2 + d2);
            float sA = sinr(fr1 + d1);
            float sB = sinr(fmaf(bv, s2, fr3 + d3));
            float harm = ampv * mixv;
            arr[j] = fmaf(harm, sB, (ampv - harm) * sA);
        }
    }

    // head-mean: butterfly over lane bits 0..2
    #pragma unroll
    for (int m = 1; m <= 4; m <<= 1) {
        #pragma unroll
        for (int j = 0; j < CELL; ++j) arr[j] += __shfl_xor(arr[j], m);
    }
    if (h == 0) {
        float4* op = reinterpret_cast<float4*>(out + (size_t)bb * NS + i0);
        #pragma unroll
        for (int j4 = 0; j4 < CELL / 4; ++j4)
            op[j4] = make_float4(arr[j4 * 4 + 0] * 0.125f, arr[j4 * 4 + 1] * 0.125f,
                                 arr[j4 * 4 + 2] * 0.125f, arr[j4 * 4 + 3] * 0.125f);
    }
}

extern "C" void kernel_launch(void* const* d_in, const int* in_sizes, int n_in,
                              void* d_out, int out_size, void* d_ws, size_t ws_size,
                              hipStream_t stream) {
    const float* x     = (const float*)d_in[0];
    const float* noise = (const float*)d_in[1];
    float* out = (float*)d_out;
    // workspace: chunk sums 256KB | bins f32 384KB | anchors f32 96KB
    float* chunkS = (float*)d_ws;                               // [128][256][2]
    float* binsG  = (float*)((char*)d_ws + 262144);             // [128][6][128]
    float* frG    = (float*)((char*)d_ws + 262144 + 393216);    // [128][64][3]
    sum_kernel<<<NSEQ * 32, TPB, 0, stream>>>(noise, chunkS);
    anchor_kernel<<<NSEQ, TPB, 0, stream>>>(x, chunkS, binsG, frG);
    fm_kernel<<<NBATCH * NPARTS, TPB, 0, stream>>>(noise, binsG, frG, out);
}

// Round 4
// 80.441 us; speedup vs baseline: 1.7464x; 1.0141x over previous
//
#include <hip/hip_runtime.h>
#include <math.h>

#define NS      32768            // samples per sequence
#define NB      128              // interpolation bins
#define NSEQ    128              // 16 batch x 8 heads
#define NCHUNK  256              // 128-sample chunks per sequence
#define CHUNK   128
#define CELL    16               // samples per thread-cell in synth
#define PART    512              // samples per block per head (multiple of 256)
#define NPARTS  (NS / PART)      // 64
#define TPB     256
#define NBATCH  16
#define NBIN    4                // bins spanned by one 512-sample part
#define SJ      ((CELL * (CELL - 1)) / 2)   // 120

// sin(2*pi*x): v_sin_f32 takes revolutions; reduce to [-0.5, 0.5] first
__device__ __forceinline__ float sinr(float x) {
    return __builtin_amdgcn_sinf(x - rintf(x));
}

// f32 linear-interp segment params for a 16-aligned cell at sample i
__device__ __forceinline__ void seg_params_f(int i, int& lo, int& hi,
                                             float& w0, float& wst) {
    if (i < 128)            { lo = 0;   hi = 1;   w0 = 0.f; wst = 0.f; }
    else if (i >= NS - 128) { lo = 127; hi = 127; w0 = 0.f; wst = 0.f; }
    else {
        lo = (i - 128) >> 8;  hi = lo + 1;
        int off = (i - 128) & 255;
        w0 = (float)(off + 0.5f) * (1.0f / 256.0f);
        wst = 1.0f / 256.0f;
    }
}

// bin value for stream q at bin j; phase streams (f0, std, modf) and b are
// pre-scaled to revolutions so all downstream phase math is in revolutions
__device__ __forceinline__ double bin_value(const float* xs, int q, int j) {
    const double PI_    = 3.14159265358979323846;
    const double INV2PI = 0.15915494309189533576888376337251;
    const double MINF   = 40.0 / 11025.0;
    const double FRNG   = (4000.0 - 40.0) / 11025.0;
    if (q == 0) {                                   // amp (unscaled)
        double a0 = (double)xs[j], a1 = (double)xs[NB + j];
        return sqrt(a0 * a0 + a1 * a1);
    }
    double ang = atan2((double)xs[(2 * q - 1) * NB + j],
                       (double)xs[(2 * q - 2) * NB + j]) / PI_;
    double sh, sc;
    if      (q == 1) { sh = MINF; sc = FRNG; }      // f0
    else if (q == 2) { sh = 1.0;  sc = 0.5;  }      // mix (amplitude, unscaled)
    else if (q == 3) { sh = MINF; sc = FRNG; }      // noise_std
    else if (q == 4) { sh = 0.25; sc = 4.75; }      // mod_factor
    else             { sh = 0.1;  sc = 9.9;  }      // b
    double v = sh + ang * sc;
    if (q != 2) v *= INV2PI;
    return v;
}

// ---- K1 (fused pre): one block per sequence. Thread c reads chunk c of the
// noise directly (S0, S1), all bins computed once, f64 closed-form chunk scan
// -> f32 bins + fractional f32 anchors at every part boundary.
// Chunk c closed forms (chunks 1..254: segment k=(c-1)>>1, half hf=(c-1)&1):
//   sum(w) over chunk = 64*hf + 32 ;  sum(w*n) = ((128*hf+0.5)*S0 + S1)/256
__global__ __launch_bounds__(TPB)
void pre_kernel(const float* __restrict__ xg, const float* __restrict__ ng,
                float* __restrict__ binsG, float* __restrict__ frG) {
    __shared__ double bf[3][NB];     // f0, std, modf (revolutions, f64)
    __shared__ double wsum[4][3];

    int seq = blockIdx.x;            // 128
    int t = threadIdx.x;
    const float* xs = xg + (size_t)seq * 10 * NB;

    // noise chunk sums in-place (was sum_kernel): 32 float4 loads per thread,
    // independent of the bin math below -> latency overlaps across waves
    const float4* np_ = reinterpret_cast<const float4*>(
        ng + (size_t)seq * NS + (size_t)t * CHUNK);
    float s0 = 0.f, s1 = 0.f;
    #pragma unroll 8
    for (int j = 0; j < CHUNK / 4; ++j) {
        float4 v = np_[j];
        float jd = (float)(j * 4);
        s0 += v.x; s1 = fmaf(jd,       v.x, s1);
        s0 += v.y; s1 = fmaf(jd + 1.f, v.y, s1);
        s0 += v.z; s1 = fmaf(jd + 2.f, v.z, s1);
        s0 += v.w; s1 = fmaf(jd + 3.f, v.w, s1);
    }

    for (int idx = t; idx < 6 * NB; idx += TPB) {
        int q = idx >> 7, j = idx & (NB - 1);
        double v = bin_value(xs, q, j);
        binsG[((size_t)seq * 6 + q) * NB + j] = (float)v;
        if      (q == 1) bf[0][j] = v;
        else if (q == 3) bf[1][j] = v;
        else if (q == 4) bf[2][j] = v;
    }
    __syncthreads();

    int c = t;                       // thread c owns chunk c (0..255)
    double S0 = (double)s0, S1 = (double)s1;
    double t1, t3, t2;
    if (c == 0) {                                    // flat head: value = bin 0
        t3 = 128.0 * bf[0][0];
        t2 = 128.0 * bf[2][0];
        t1 = t3 + bf[1][0] * S0;
    } else if (c == NCHUNK - 1) {                    // flat tail: value = bin 127
        t3 = 128.0 * bf[0][NB - 1];
        t2 = 128.0 * bf[2][NB - 1];
        t1 = t3 + bf[1][NB - 1] * S0;
    } else {
        int k = (c - 1) >> 1, hf = (c - 1) & 1;
        double sw  = 64.0 * (double)hf + 32.0;
        double f0L = bf[0][k], dF0 = bf[0][k + 1] - f0L;
        double stL = bf[1][k], dSt = bf[1][k + 1] - stL;
        double mfL = bf[2][k], dMf = bf[2][k + 1] - mfL;
        t3 = 128.0 * f0L + dF0 * sw;
        t2 = 128.0 * mfL + dMf * sw;
        t1 = t3 + stL * S0
                + dSt * ((128.0 * (double)hf + 0.5) * S0 + S1) * (1.0 / 256.0);
    }

    // inclusive scan over 256 chunks: in-wave + cross-wave combine
    int lane = t & 63, wid = t >> 6;
    double v1 = t1, v3 = t3, v2 = t2;
    #pragma unroll
    for (int d = 1; d < 64; d <<= 1) {
        double u1 = __shfl_up(v1, d);
        double u3 = __shfl_up(v3, d);
        double u2 = __shfl_up(v2, d);
        if (lane >= d) { v1 += u1; v3 += u3; v2 += u2; }
    }
    if (lane == 63) { wsum[wid][0] = v1; wsum[wid][1] = v3; wsum[wid][2] = v2; }
    __syncthreads();
    double b1 = 0.0, b3 = 0.0, b2 = 0.0;
    #pragma unroll
    for (int k = 0; k < 3; ++k)
        if (wid > k) { b1 += wsum[k][0]; b3 += wsum[k][1]; b2 += wsum[k][2]; }
    v1 += b1; v3 += b3; v2 += b2;

    // part p starts at chunk 4p -> anchor = inclusive prefix through chunk 4p-1
    if ((c & 3) == 3 && c < 4 * (NPARTS - 1)) {      // c = 3..251 -> p = 1..63
        int p = (c >> 2) + 1;
        float* o = frG + ((size_t)seq * NPARTS + p) * 3;
        o[0] = (float)(v1 - rint(v1));
        o[1] = (float)(v3 - rint(v3));
        o[2] = (float)(v2 - rint(v2));
    }
    if (c == 0) {                                    // p = 0 anchor is zero
        float* o = frG + (size_t)seq * NPARTS * 3;
        o[0] = 0.f; o[1] = 0.f; o[2] = 0.f;
    }
}

// ---- K2: synth. No f64, no atan2, no lookback: bins + fractional anchors
// come precomputed. In-part f32 scan (max ~370 rev -> ulp 3e-5, << tol).
__global__ __launch_bounds__(TPB, 4)
void fm_kernel(const float* __restrict__ ng, const float* __restrict__ binsG,
               const float* __restrict__ frG, float* __restrict__ out) {
    __shared__ float binsB[8][6][NBIN];
    __shared__ float frL[8][3];
    __shared__ float wtot[4][8][3];

    int bx = blockIdx.x;                  // 1024 = NBATCH * NPARTS
    int bb = bx >> 6, p = bx & (NPARTS - 1);
    int tid = threadIdx.x, lane = tid & 63, wid = tid >> 6;
    int h = tid & 7, c = tid >> 3;        // butterfly needs h in lane bits 0..2
    int P = p * PART;
    int b0 = (P - 128) >> 8; if (b0 < 0) b0 = 0;
    int s  = (bb << 3) + h;
    int i0 = P + c * CELL;

    // noise loads first: HBM latency hides under the (tiny) staging phase
    const float4* np_ = reinterpret_cast<const float4*>(ng + (size_t)s * NS + i0);
    float4 nv[CELL / 4];
    #pragma unroll
    for (int q4 = 0; q4 < CELL / 4; ++q4) nv[q4] = np_[q4];

    // stage f32 bins (8h x 6q x 4bins = 192) and anchors (8h x 3 = 24)
    if (tid < 192) {
        int j = tid & 3, q = (tid >> 2) % 6, h2 = tid / 24;
        binsB[h2][q][j] =
            binsG[((size_t)((bb << 3) + h2) * 6 + q) * NB + min(b0 + j, NB - 1)];
    }
    if (tid < 24) {
        int k = tid % 3, h2 = tid / 3;
        frL[h2][k] = frG[((size_t)((bb << 3) + h2) * NPARTS + p) * 3 + k];
    }
    __syncthreads();

    int lo, hi; float w0, wst;
    seg_params_f(i0, lo, hi, w0, wst);
    int jL = lo - b0, jH = hi - b0;

    float amL = binsB[h][0][jL], dAm = binsB[h][0][jH] - amL;
    float g0L = binsB[h][1][jL], gF0 = binsB[h][1][jH] - g0L;
    float mxL = binsB[h][2][jL], dMx = binsB[h][2][jH] - mxL;
    float gsL = binsB[h][3][jL], gSt = binsB[h][3][jH] - gsL;
    float gmL = binsB[h][4][jL], gMf = binsB[h][4][jH] - gmL;
    float bbL = binsB[h][5][jL], dBb = binsB[h][5][jH] - bbL;

    // f32 cell totals over CELL samples
    float s0 = 0.f, s1 = 0.f;
    #pragma unroll
    for (int q4 = 0; q4 < CELL / 4; ++q4) {
        float jd = (float)(q4 * 4);
        s0 += nv[q4].x; s1 = fmaf(jd,       nv[q4].x, s1);
        s0 += nv[q4].y; s1 = fmaf(jd + 1.f, nv[q4].y, s1);
        s0 += nv[q4].z; s1 = fmaf(jd + 2.f, nv[q4].z, s1);
        s0 += nv[q4].w; s1 = fmaf(jd + 3.f, nv[q4].w, s1);
    }
    float sw = (float)CELL * w0 + (float)SJ * wst;
    float t3 = (float)CELL * g0L + gF0 * sw;
    float t2 = (float)CELL * gmL + gMf * sw;
    float t1 = t3 + gsL * s0 + gSt * fmaf(w0, s0, wst * s1);

    // in-part scan: stride-8 wave scan (head lane fixed) + cross-wave combine
    float v1 = t1, v3 = t3, v2 = t2;
    #pragma unroll
    for (int d = 8; d < 64; d <<= 1) {
        float u1 = __shfl_up(v1, d);
        float u3 = __shfl_up(v3, d);
        float u2 = __shfl_up(v2, d);
        if (lane >= d) { v1 += u1; v3 += u3; v2 += u2; }
    }
    if (lane >= 56) { wtot[wid][h][0] = v1; wtot[wid][h][1] = v3; wtot[wid][h][2] = v2; }
    __syncthreads();
    float b1 = 0.f, b3 = 0.f, b2 = 0.f;
    #pragma unroll
    for (int k = 0; k < 3; ++k)
        if (wid > k) { b1 += wtot[k][h][0]; b3 += wtot[k][h][1]; b2 += wtot[k][h][2]; }

    // cell-start phases (anchor + exclusive in-part prefix), reduced mod 1
    float fr1 = frL[h][0] + b1 + (v1 - t1); fr1 -= rintf(fr1);
    float fr3 = frL[h][1] + b3 + (v3 - t3); fr3 -= rintf(fr3);
    float fr2 = frL[h][2] + b2 + (v2 - t2); fr2 -= rintf(fr2);

    float arr[CELL];
    float d1 = 0.f, d2 = 0.f, d3 = 0.f;
    #pragma unroll
    for (int q4 = 0; q4 < CELL / 4; ++q4) {
        float nf[4] = {nv[q4].x, nv[q4].y, nv[q4].z, nv[q4].w};
        #pragma unroll
        for (int u = 0; u < 4; ++u) {
            int j = q4 * 4 + u;
            float wf  = fmaf((float)j, wst, w0);
            float f0v = fmaf(wf, gF0, g0L);
            float stv = fmaf(wf, gSt, gsL);
            float mfv = fmaf(wf, gMf, gmL);
            d3 += f0v;                       // cs3 (rev, relative to anchor)
            d1 += fmaf(nf[u], stv, f0v);     // cs1
            d2 += mfv;                       // cs2
            float ampv = fmaf(wf, dAm, amL);
            float mixv = fmaf(wf, dMx, mxL);
            float bv   = fmaf(wf, dBb, bbL);
            float s2 = sinr(fr2 + d2);
            float sA = sinr(fr1 + d1);
            float sB = sinr(fmaf(bv, s2, fr3 + d3));
            float harm = ampv * mixv;
            arr[j] = fmaf(harm, sB, (ampv - harm) * sA);
        }
    }

    // head-mean: butterfly over lane bits 0..2
    #pragma unroll
    for (int m = 1; m <= 4; m <<= 1) {
        #pragma unroll
        for (int j = 0; j < CELL; ++j) arr[j] += __shfl_xor(arr[j], m);
    }
    if (h == 0) {
        float4* op = reinterpret_cast<float4*>(out + (size_t)bb * NS + i0);
        #pragma unroll
        for (int j4 = 0; j4 < CELL / 4; ++j4)
            op[j4] = make_float4(arr[j4 * 4 + 0] * 0.125f, arr[j4 * 4 + 1] * 0.125f,
                                 arr[j4 * 4 + 2] * 0.125f, arr[j4 * 4 + 3] * 0.125f);
    }
}

extern "C" void kernel_launch(void* const* d_in, const int* in_sizes, int n_in,
                              void* d_out, int out_size, void* d_ws, size_t ws_size,
                              hipStream_t stream) {
    const float* x     = (const float*)d_in[0];
    const float* noise = (const float*)d_in[1];
    float* out = (float*)d_out;
    // workspace: bins f32 384KB | anchors f32 96KB
    float* binsG = (float*)d_ws;                        // [128][6][128]
    float* frG   = (float*)((char*)d_ws + 393216);      // [128][64][3]
    pre_kernel<<<NSEQ, TPB, 0, stream>>>(x, noise, binsG, frG);
    fm_kernel<<<NBATCH * NPARTS, TPB, 0, stream>>>(noise, binsG, frG, out);
}